// Round 1
// baseline (844.786 us; speedup 1.0000x reference)
//
#include <hip/hip_runtime.h>
#include <cstdint>
#include <cstddef>

// ---------------------------------------------------------------------------
// SCCA: dual cross-attention with 2-slot KV per token. bf16 MFMA pipeline.
// B=8, N=8192, C=256, H=8, hd=32.  BN = 65536 tokens per direction.
// ---------------------------------------------------------------------------

typedef __attribute__((ext_vector_type(4))) float  f32x4;
typedef __attribute__((ext_vector_type(8))) short  short8;
typedef __attribute__((ext_vector_type(4))) float  float4_t;
typedef __attribute__((ext_vector_type(4))) unsigned short ushort4_t;

__device__ __forceinline__ float b2f(unsigned short u) {
  unsigned int x = ((unsigned int)u) << 16;
  return __builtin_bit_cast(float, x);
}
__device__ __forceinline__ unsigned short f2b(float f) {
  unsigned int u = __builtin_bit_cast(unsigned int, f);
  unsigned int r = (u + 0x7fffu + ((u >> 16) & 1u)) >> 16;  // RNE
  return (unsigned short)r;
}

__device__ __forceinline__ void async16(const void* g, void* l) {
  __builtin_amdgcn_global_load_lds(
      (const __attribute__((address_space(1))) void*)g,
      (__attribute__((address_space(3))) void*)l, 16, 0, 0);
}

// ---------------------------------------------------------------------------
// GEMM: out[M,N] = epi( sum_pairs A_p[M,256] @ W_p[N,256]^T + bias[N] )
// A row-major lda=256 (bf16).  W row-major [N, ldw] (bf16), k-offset kb per
// pair.  Tile 128x128, BK=32, 4 waves (each 64x64 = 4x4 frags of 16x16x32).
// EPI: 0 = bf16 store, 1 = exact-erf GELU -> bf16, 2 = +residual -> fp32.
// ---------------------------------------------------------------------------
template <int EPI>
__global__ __launch_bounds__(256)
void gemm_bt(const unsigned short* __restrict__ A1,
             const unsigned short* __restrict__ A2,
             const unsigned short* __restrict__ W,
             int ldw, int koff2, int npairs,
             const float* __restrict__ bias,
             const float* __restrict__ res,
             void* __restrict__ outp, int ldo)
{
  __shared__ unsigned short Asm[128 * 32];
  __shared__ unsigned short Wsm[128 * 32];

  const int t = threadIdx.x;
  const size_t Arow0 = (size_t)blockIdx.x * 128;
  const int    Wrow0 = blockIdx.y * 128;

  const int l  = t & 63;
  const int wv = t >> 6;
  const int wr = (wv >> 1) * 64;   // wave row offset in tile
  const int wc = (wv & 1) * 64;    // wave col offset in tile
  const int lr = l & 15;
  const int kc = (l >> 4) * 8;

  const int srow = t >> 2;         // staging: 64 rows per 256-thread pass
  const int scol = (t & 3) * 8;    // 8 bf16 = 16 B per lane

  f32x4 acc[4][4] = {};

  for (int p = 0; p < npairs; ++p) {
    const unsigned short* A = p ? A2 : A1;
    const int kb = p ? koff2 : 0;
    for (int kt = 0; kt < 8; ++kt) {
      const int k0 = kt * 32;
      __syncthreads();
      async16(&A[(Arow0 + srow) * 256 + (k0 + scol)],        &Asm[srow * 32 + scol]);
      async16(&A[(Arow0 + 64 + srow) * 256 + (k0 + scol)],   &Asm[(64 + srow) * 32 + scol]);
      async16(&W[(size_t)(Wrow0 + srow) * ldw + (kb + k0 + scol)],      &Wsm[srow * 32 + scol]);
      async16(&W[(size_t)(Wrow0 + 64 + srow) * ldw + (kb + k0 + scol)], &Wsm[(64 + srow) * 32 + scol]);
      __syncthreads();

      short8 af[4], bfr[4];
#pragma unroll
      for (int m = 0; m < 4; ++m)
        af[m] = *(const short8*)&Asm[(wr + m * 16 + lr) * 32 + kc];
#pragma unroll
      for (int n = 0; n < 4; ++n)
        bfr[n] = *(const short8*)&Wsm[(wc + n * 16 + lr) * 32 + kc];
#pragma unroll
      for (int m = 0; m < 4; ++m)
#pragma unroll
        for (int n = 0; n < 4; ++n)
          acc[m][n] = __builtin_amdgcn_mfma_f32_16x16x32_bf16(af[m], bfr[n], acc[m][n], 0, 0, 0);
    }
  }

  // Epilogue.  C/D layout (verified m89): col = lane&15, row = (lane>>4)*4+reg.
  const int lq = l >> 4;
#pragma unroll
  for (int m = 0; m < 4; ++m) {
#pragma unroll
    for (int n = 0; n < 4; ++n) {
#pragma unroll
      for (int r = 0; r < 4; ++r) {
        size_t row = Arow0 + wr + m * 16 + lq * 4 + r;
        int col = Wrow0 + wc + n * 16 + lr;
        float v = acc[m][n][r] + bias[col];
        if (EPI == 1)
          v = 0.5f * v * (1.0f + erff(v * 0.70710678118654752f));
        if (EPI == 2)
          ((float*)outp)[row * (size_t)ldo + col] = v + res[row * 256 + col];
        else
          ((unsigned short*)outp)[row * (size_t)ldo + col] = f2b(v);
      }
    }
  }
}

// fp32 -> bf16 convert (n multiple of 4)
__global__ __launch_bounds__(256)
void cvt_bf16(const float* __restrict__ src, unsigned short* __restrict__ dst, int n)
{
  int i = (blockIdx.x * 256 + threadIdx.x) * 4;
  if (i >= n) return;
  float4_t v = *(const float4_t*)(src + i);
  ushort4_t o;
  o[0] = f2b(v[0]); o[1] = f2b(v[1]); o[2] = f2b(v[2]); o[3] = f2b(v[3]);
  *(ushort4_t*)(dst + i) = o;
}

// in-place softmax over rows of 256 bf16; one wave per row, 4 rows per block
__global__ __launch_bounds__(256)
void softmax_rows(unsigned short* __restrict__ buf)
{
  int row = blockIdx.x * 4 + (threadIdx.x >> 6);
  int l = threadIdx.x & 63;
  unsigned short* p = buf + (size_t)row * 256;
  float v[4];
#pragma unroll
  for (int j = 0; j < 4; ++j) v[j] = b2f(p[l + 64 * j]);
  float mx = fmaxf(fmaxf(v[0], v[1]), fmaxf(v[2], v[3]));
#pragma unroll
  for (int off = 32; off > 0; off >>= 1) mx = fmaxf(mx, __shfl_xor(mx, off, 64));
  float s = 0.f;
#pragma unroll
  for (int j = 0; j < 4; ++j) { v[j] = expf(v[j] - mx); s += v[j]; }
#pragma unroll
  for (int off = 32; off > 0; off >>= 1) s += __shfl_xor(s, off, 64);
  float inv = 1.f / s;
#pragma unroll
  for (int j = 0; j < 4; ++j) p[l + 64 * j] = f2b(v[j] * inv);
}

// o = a * b elementwise (bf16), 8 elems/thread
__global__ __launch_bounds__(256)
void mul_bf16(const unsigned short* __restrict__ a,
              const unsigned short* __restrict__ b,
              unsigned short* __restrict__ o)
{
  size_t i = ((size_t)blockIdx.x * 256 + threadIdx.x) * 8;
  short8 va = *(const short8*)(a + i);
  short8 vb = *(const short8*)(b + i);
  short8 vo;
#pragma unroll
  for (int j = 0; j < 8; ++j)
    vo[j] = (short)f2b(b2f((unsigned short)va[j]) * b2f((unsigned short)vb[j]));
  *(short8*)(o + i) = vo;
}

// per-(token,head) 2-slot attention: softmax([q.k0, q.k1]/sqrt(32)) @ [v0;v1]
__global__ __launch_bounds__(256)
void attn2(const unsigned short* __restrict__ qkv,   // [BN,768] : q|k0|v0
           const unsigned short* __restrict__ k1b,   // [BN,256]
           const unsigned short* __restrict__ v1b,   // [BN,256]
           unsigned short* __restrict__ ctx)         // [BN,256]
{
  int tid = blockIdx.x * 256 + threadIdx.x;
  int tok = tid >> 3;
  int h = tid & 7;
  const unsigned short* q   = qkv + (size_t)tok * 768 + h * 32;
  const unsigned short* k0p = q + 256;
  const unsigned short* v0p = q + 512;
  const unsigned short* k1p = k1b + (size_t)tok * 256 + h * 32;
  const unsigned short* v1p = v1b + (size_t)tok * 256 + h * 32;
  unsigned short* op = ctx + (size_t)tok * 256 + h * 32;

  float s0 = 0.f, s1 = 0.f;
#pragma unroll
  for (int c = 0; c < 4; ++c) {
    short8 q8 = *(const short8*)(q + c * 8);
    short8 a8 = *(const short8*)(k0p + c * 8);
    short8 b8 = *(const short8*)(k1p + c * 8);
#pragma unroll
    for (int j = 0; j < 8; ++j) {
      float qf = b2f((unsigned short)q8[j]);
      s0 += qf * b2f((unsigned short)a8[j]);
      s1 += qf * b2f((unsigned short)b8[j]);
    }
  }
  const float sc = 0.17677669529663687f;  // 1/sqrt(32)
  s0 *= sc; s1 *= sc;
  float mx = fmaxf(s0, s1);
  float e0 = expf(s0 - mx), e1 = expf(s1 - mx);
  float inv = 1.f / (e0 + e1);
  e0 *= inv; e1 *= inv;
#pragma unroll
  for (int c = 0; c < 4; ++c) {
    short8 a8 = *(const short8*)(v0p + c * 8);
    short8 b8 = *(const short8*)(v1p + c * 8);
    short8 o8;
#pragma unroll
    for (int j = 0; j < 8; ++j)
      o8[j] = (short)f2b(e0 * b2f((unsigned short)a8[j]) + e1 * b2f((unsigned short)b8[j]));
    *(short8*)(op + c * 8) = o8;
  }
}

// rv[768]: rv[0:256)=bq ; rv[256:512)=bk + kn[d]@Wk^T ; rv[512:768)=bv + vn[d]@Wv^T
__global__ __launch_bounds__(256)
void rowvec_k(const float* __restrict__ in_w, const float* __restrict__ in_b,
              const float* __restrict__ kn, const float* __restrict__ vn,
              int drow, float* __restrict__ rv)
{
  int j = blockIdx.x * 256 + threadIdx.x;   // 0..767
  float v = in_b[j];
  if (j >= 256) {
    const float* nz = (j < 512 ? kn : vn) + drow * 256;
    const float* wrow = in_w + (size_t)j * 256;
    float s = 0.f;
    for (int k = 0; k < 256; ++k) s += nz[k] * wrow[k];
    v += s;
  }
  rv[j] = v;
}

extern "C" void kernel_launch(void* const* d_in, const int* in_sizes, int n_in,
                              void* d_out, int out_size, void* d_ws, size_t ws_size,
                              hipStream_t stream)
{
  const float* x0     = (const float*)d_in[0];
  const float* x1     = (const float*)d_in[1];
  const float* fc1_w  = (const float*)d_in[2];
  const float* fc1_b  = (const float*)d_in[3];
  const float* fc2_w  = (const float*)d_in[4];
  const float* fc2_b  = (const float*)d_in[5];
  const float* in_w01 = (const float*)d_in[6];
  const float* in_b01 = (const float*)d_in[7];
  const float* out_w01= (const float*)d_in[8];
  const float* out_b01= (const float*)d_in[9];
  const float* in_w10 = (const float*)d_in[10];
  const float* in_b10 = (const float*)d_in[11];
  const float* out_w10= (const float*)d_in[12];
  const float* out_b10= (const float*)d_in[13];
  const float* kn     = (const float*)d_in[14];
  const float* vn     = (const float*)d_in[15];

  const size_t BN = (size_t)8 * 8192;   // 65536
  const size_t NC = BN * 256;           // 16,777,216 elems per [BN,256]

  // -------- workspace layout (all 256B-aligned) ------------------------
  char* ws = (char*)d_ws;
  unsigned short* xb0   = (unsigned short*)ws; ws += NC * 2;
  unsigned short* xb1   = (unsigned short*)ws; ws += NC * 2;
  unsigned short* wfc1  = (unsigned short*)ws; ws += 131072 * 2;
  unsigned short* wfc2  = (unsigned short*)ws; ws += 65536 * 2;
  unsigned short* win01 = (unsigned short*)ws; ws += 196608 * 2;
  unsigned short* wout01= (unsigned short*)ws; ws += 65536 * 2;
  unsigned short* win10 = (unsigned short*)ws; ws += 196608 * 2;
  unsigned short* wout10= (unsigned short*)ws; ws += 65536 * 2;
  float* rv01 = (float*)ws; ws += 768 * 4;
  float* rv10 = (float*)ws; ws += 768 * 4;
  unsigned short* bufA = (unsigned short*)ws; ws += NC * 2;   // h, then k1in
  unsigned short* bufB = (unsigned short*)ws; ws += NC * 2;   // s/rel, then ctx
  unsigned short* k1b  = (unsigned short*)ws; ws += NC * 2;
  unsigned short* v1b  = (unsigned short*)ws; ws += NC * 2;
  unsigned short* qkv  = (unsigned short*)ws; ws += BN * 768 * 2;

  size_t need = (size_t)(ws - (char*)d_ws);
  if (ws_size < need) return;   // insufficient scratch -> visible failure

  dim3 blk(256);

  // -------- prep: bf16 conversions + const rows ------------------------
  cvt_bf16<<<16384, blk, 0, stream>>>(x0, xb0, (int)NC);
  cvt_bf16<<<16384, blk, 0, stream>>>(x1, xb1, (int)NC);
  cvt_bf16<<<128, blk, 0, stream>>>(fc1_w, wfc1, 131072);
  cvt_bf16<<<64,  blk, 0, stream>>>(fc2_w, wfc2, 65536);
  cvt_bf16<<<192, blk, 0, stream>>>(in_w01, win01, 196608);
  cvt_bf16<<<64,  blk, 0, stream>>>(out_w01, wout01, 65536);
  cvt_bf16<<<192, blk, 0, stream>>>(in_w10, win10, 196608);
  cvt_bf16<<<64,  blk, 0, stream>>>(out_w10, wout10, 65536);
  rowvec_k<<<3, blk, 0, stream>>>(in_w01, in_b01, kn, vn, 0, rv01);
  rowvec_k<<<3, blk, 0, stream>>>(in_w10, in_b10, kn, vn, 1, rv10);

  // -------- per direction ---------------------------------------------
  for (int d = 0; d < 2; ++d) {
    const unsigned short* xa  = d ? xb1 : xb0;     // "a" = query side
    const unsigned short* xo  = d ? xb0 : xb1;     // "b" = other side
    const float* xaf  = d ? x1 : x0;               // residual (fp32)
    const unsigned short* win  = d ? win10 : win01;
    const unsigned short* wout = d ? wout10 : wout01;
    const float* inb  = d ? in_b10 : in_b01;
    const float* outb = d ? out_b10 : out_b01;
    const float* rv   = d ? rv10 : rv01;
    float* outp = (float*)d_out + (size_t)d * NC;

    dim3 g2(512, 2), g6(512, 6);

    // h = gelu([a|b] @ fc1_w^T + fc1_b)         [BN,256] bf16
    gemm_bt<1><<<g2, blk, 0, stream>>>(xa, xo, wfc1, 512, 256, 2,
                                       fc1_b, nullptr, bufA, 256);
    // s = h @ fc2_w^T + fc2_b                   [BN,256] bf16
    gemm_bt<0><<<g2, blk, 0, stream>>>(bufA, nullptr, wfc2, 256, 0, 1,
                                       fc2_b, nullptr, bufB, 256);
    // rel = softmax(s) (in place)
    softmax_rows<<<16384, blk, 0, stream>>>(bufB);
    // k1in = a * rel                            [BN,256] bf16 (reuse bufA)
    mul_bf16<<<8192, blk, 0, stream>>>(xa, bufB, bufA);
    // qkv = a @ Wi^T + rowvec (q|K0|V0)         [BN,768] bf16
    gemm_bt<0><<<g6, blk, 0, stream>>>(xa, nullptr, win, 256, 0, 1,
                                       rv, nullptr, qkv, 768);
    // K1 = k1in @ Wk^T + bk                     [BN,256] bf16
    gemm_bt<0><<<g2, blk, 0, stream>>>(bufA, nullptr, win + 256 * 256, 256, 0, 1,
                                       inb + 256, nullptr, k1b, 256);
    // V1 = b @ Wv^T + bv                        [BN,256] bf16
    gemm_bt<0><<<g2, blk, 0, stream>>>(xo, nullptr, win + 512 * 256, 256, 0, 1,
                                       inb + 512, nullptr, v1b, 256);
    // ctx (reuse bufB)
    attn2<<<2048, blk, 0, stream>>>(qkv, k1b, v1b, bufB);
    // out = ctx @ Wo^T + bo + x                 [BN,256] fp32 -> d_out
    gemm_bt<2><<<g2, blk, 0, stream>>>(bufB, nullptr, wout, 256, 0, 1,
                                       outb, xaf, outp, 256);
  }
}

// Round 2
// 751.805 us; speedup vs baseline: 1.1237x; 1.1237x over previous
//
#include <hip/hip_runtime.h>
#include <cstdint>
#include <cstddef>

// ---------------------------------------------------------------------------
// SCCA: dual cross-attention, 2-slot KV per token. bf16 MFMA pipeline.
// B=8, N=8192, C=256, H=8, hd=32.  BN=65536 tokens/dir, TBN=131072 total.
//
// Round 2: both directions batched into every launch; qkv+V1+fc1 merged into
// one mega-GEMM; XCD+chunk block swizzle for A-panel L2 reuse; st-style XOR
// LDS swizzle (both-sides: pre-swizzled global src for global_load_lds +
// swizzled ds_read) to kill the 8-way bank conflict of [128][32] tiles.
// ---------------------------------------------------------------------------

#define BNv  65536
#define TBNv 131072
#define NCv  16777216ull   // BN*256

typedef __attribute__((ext_vector_type(4))) float  f32x4;
typedef __attribute__((ext_vector_type(8))) short  short8;
typedef __attribute__((ext_vector_type(4))) float  float4_t;
typedef __attribute__((ext_vector_type(4))) unsigned short ushort4_t;

__device__ __forceinline__ float b2f(unsigned short u) {
  unsigned int x = ((unsigned int)u) << 16;
  return __builtin_bit_cast(float, x);
}
__device__ __forceinline__ unsigned short f2b(float f) {
  unsigned int u = __builtin_bit_cast(unsigned int, f);
  unsigned int r = (u + 0x7fffu + ((u >> 16) & 1u)) >> 16;  // RNE
  return (unsigned short)r;
}

__device__ __forceinline__ void async16(const void* g, void* l) {
  __builtin_amdgcn_global_load_lds(
      (const __attribute__((address_space(1))) void*)g,
      (__attribute__((address_space(3))) void*)l, 16, 0, 0);
}

// ---------------------------------------------------------------------------
// Core 128x128 tile K-loop. A row-major lda=256; W row-major [*, ldw].
// LDS layout: linear [128][32] bf16, but 16B slots are XOR-swizzled:
//   LDS slot sl of row r holds global slot (sl ^ ((r>>1)&3)).
// Staging pre-swizzles the GLOBAL source column; reads swizzle the ds addr.
// ---------------------------------------------------------------------------
__device__ __forceinline__ void mfma_loop(
    const unsigned short* __restrict__ A1,
    const unsigned short* __restrict__ A2,
    const unsigned short* __restrict__ W,
    int ldw, int koff2, int npairs,
    size_t Arow0, int Wrow0,
    unsigned short* Asm, unsigned short* Wsm,
    f32x4 (&acc)[4][4], int t)
{
  const int l  = t & 63;
  const int wv = t >> 6;
  const int wr = (wv >> 1) * 64;
  const int wc = (wv & 1) * 64;
  const int lr = l & 15;
  // swizzled ds_read column (elems): (lq ^ ((lr>>1)&3)) * 8
  const int kcS = (((l >> 4) ^ ((lr >> 1) & 3)) * 8);

  const int srow  = t >> 2;                              // staging row 0..63
  const int scolS = (((t & 3) ^ ((t >> 3) & 3)) * 8);    // pre-swizzled global col
  const int ldst  = t * 8;                               // linear LDS elems (=t*16B)

  for (int p = 0; p < npairs; ++p) {
    const unsigned short* A = p ? A2 : A1;
    const int kb = p ? koff2 : 0;
    for (int kt = 0; kt < 8; ++kt) {
      const int k0 = kt * 32;
      __syncthreads();
      async16(&A[(Arow0 + srow) * 256 + (size_t)(k0 + scolS)],        &Asm[ldst]);
      async16(&A[(Arow0 + 64 + srow) * 256 + (size_t)(k0 + scolS)],   &Asm[64 * 32 + ldst]);
      async16(&W[(size_t)(Wrow0 + srow) * ldw + (kb + k0 + scolS)],      &Wsm[ldst]);
      async16(&W[(size_t)(Wrow0 + 64 + srow) * ldw + (kb + k0 + scolS)], &Wsm[64 * 32 + ldst]);
      __syncthreads();

      short8 af[4], bfr[4];
#pragma unroll
      for (int m = 0; m < 4; ++m)
        af[m] = *(const short8*)&Asm[(wr + m * 16 + lr) * 32 + kcS];
#pragma unroll
      for (int n = 0; n < 4; ++n)
        bfr[n] = *(const short8*)&Wsm[(wc + n * 16 + lr) * 32 + kcS];
#pragma unroll
      for (int m = 0; m < 4; ++m)
#pragma unroll
        for (int n = 0; n < 4; ++n)
          acc[m][n] = __builtin_amdgcn_mfma_f32_16x16x32_bf16(af[m], bfr[n], acc[m][n], 0, 0, 0);
    }
  }
}

// Epilogue helpers. C/D layout: col = lane&15, row = (lane>>4)*4 + reg.
// EPI 0: +bias -> bf16.  1: +bias, exact GELU -> bf16.  2: +bias +res -> fp32.
template <int EPI>
__device__ __forceinline__ void store_tile(
    f32x4 (&acc)[4][4], int t,
    const float* __restrict__ bias,     // pre-offset: bias[coli]
    const float* __restrict__ res,      // EPI2, pre-offset: res[rowi*256+coli]
    void* __restrict__ outp,            // pre-offset: out[rowi*ldo+coli]
    int ldo)
{
  const int l = t & 63, wv = t >> 6;
  const int wr = (wv >> 1) * 64, wc = (wv & 1) * 64;
  const int lr = l & 15, lq = l >> 4;
#pragma unroll
  for (int m = 0; m < 4; ++m) {
#pragma unroll
    for (int n = 0; n < 4; ++n) {
#pragma unroll
      for (int r = 0; r < 4; ++r) {
        int rowi = wr + m * 16 + lq * 4 + r;
        int coli = wc + n * 16 + lr;
        float v = acc[m][n][r] + bias[coli];
        if (EPI == 1)
          v = 0.5f * v * (1.0f + erff(v * 0.70710678118654752f));
        if (EPI == 2)
          ((float*)outp)[(size_t)rowi * ldo + coli] = v + res[(size_t)rowi * 256 + coli];
        else
          ((unsigned short*)outp)[(size_t)rowi * ldo + coli] = f2b(v);
      }
    }
  }
}

// ---------------------------------------------------------------------------
// Mega GEMM: grid 10240 = 1024 x-blocks (2 halves of 512) x 10 y-tiles.
//  y 0..5 : qkv  = x_h @ Wcat_h[0:768].T   + bcat_h      -> qkv[2BN,768]
//  y 6..7 : V1   = x_h @ Wcat_h[768:1024].T+ bcat_h      -> v1b[(1-h)*BN..]
//  y 8..9 : h    = gelu([x_h|x_o] @ wfc1.T + fc1_b)      -> hbuf[2BN,256]
// ---------------------------------------------------------------------------
__global__ __launch_bounds__(256)
void gemm_mega(const unsigned short* __restrict__ xb,      // [2BN,256]
               const unsigned short* __restrict__ Wcat0,
               const unsigned short* __restrict__ Wcat1,
               const unsigned short* __restrict__ wfc1,
               const float* __restrict__ bcat0,
               const float* __restrict__ bcat1,
               const float* __restrict__ fc1_b,
               unsigned short* __restrict__ qkv,
               unsigned short* __restrict__ v1b,
               unsigned short* __restrict__ hbuf)
{
  __shared__ unsigned short Asm[128 * 32];
  __shared__ unsigned short Wsm[128 * 32];
  const int t = threadIdx.x;

  // XCD-bijective swizzle (nwg=10240 % 8 == 0) then chunked y-fastest decode.
  const int nwg = 10240, BPC = 160;  // 16 x-blocks * 10 y
  int bid  = blockIdx.x;
  int wgid = (bid & 7) * (nwg >> 3) + (bid >> 3);
  int chunk = wgid / BPC, rem = wgid % BPC;
  int x = chunk * 16 + rem / 10;
  int y = rem % 10;

  const int half = x >> 9;
  const size_t tok0 = (size_t)(x & 511) * 128;
  const unsigned short* A1 = xb + (size_t)half * (BNv * 256);

  f32x4 acc[4][4] = {};

  if (y < 8) {
    const unsigned short* W = half ? Wcat1 : Wcat0;
    const float* bias = (half ? bcat1 : bcat0) + y * 128;
    mfma_loop(A1, nullptr, W, 256, 0, 1, tok0, y * 128, Asm, Wsm, acc, t);
    if (y < 6) {
      size_t row0 = (size_t)half * BNv + tok0;
      store_tile<0>(acc, t, bias, nullptr, qkv + row0 * 768 + y * 128, 768);
    } else {
      size_t row0 = (size_t)(1 - half) * BNv + tok0;
      store_tile<0>(acc, t, bias, nullptr, v1b + row0 * 256 + (y - 6) * 128, 256);
    }
  } else {
    const unsigned short* A2 = xb + (size_t)(1 - half) * (BNv * 256);
    mfma_loop(A1, A2, wfc1, 512, 256, 2, tok0, (y - 8) * 128, Asm, Wsm, acc, t);
    size_t row0 = (size_t)half * BNv + tok0;
    store_tile<1>(acc, t, fc1_b + (y - 8) * 128, nullptr,
                  hbuf + row0 * 256 + (y - 8) * 128, 256);
  }
}

// ---------------------------------------------------------------------------
// Generic batched GEMM: M=2BN contiguous A, N=256 (2 y-tiles), per-half W/bias.
// grid 2048 = 1024 x * 2 y.
// ---------------------------------------------------------------------------
template <int EPI>
__global__ __launch_bounds__(256)
void gemm_b2(const unsigned short* __restrict__ A,
             const unsigned short* __restrict__ W0,
             const unsigned short* __restrict__ W1,
             const float* __restrict__ b0, const float* __restrict__ b1,
             const float* __restrict__ res0, const float* __restrict__ res1,
             void* __restrict__ outp)
{
  __shared__ unsigned short Asm[128 * 32];
  __shared__ unsigned short Wsm[128 * 32];
  const int t = threadIdx.x;

  const int nwg = 2048;
  int bid  = blockIdx.x;
  int wgid = (bid & 7) * (nwg >> 3) + (bid >> 3);
  int chunk = wgid >> 5, rem = wgid & 31;   // BPC = 16*2
  int x = chunk * 16 + (rem >> 1);
  int y = rem & 1;

  const int half = x >> 9;
  const size_t row0 = (size_t)x * 128;

  f32x4 acc[4][4] = {};
  mfma_loop(A, nullptr, half ? W1 : W0, 256, 0, 1, row0, y * 128, Asm, Wsm, acc, t);

  const float* bias = (half ? b1 : b0) + y * 128;
  if (EPI == 2) {
    const float* res = (half ? res1 : res0) + (row0 - (size_t)half * BNv) * 256 + y * 128;
    store_tile<2>(acc, t, bias, res, (float*)outp + row0 * 256 + y * 128, 256);
  } else {
    store_tile<0>(acc, t, bias, nullptr,
                  (unsigned short*)outp + row0 * 256 + y * 128, 256);
  }
}

// ---------------------------------------------------------------------------
// Elementwise / prep kernels
// ---------------------------------------------------------------------------

// fp32 x0||x1 -> bf16 xb[2BN*256], 8 elems/thread
__global__ __launch_bounds__(256)
void cvt_x(const float* __restrict__ x0, const float* __restrict__ x1,
           unsigned short* __restrict__ xb)
{
  size_t i = ((size_t)blockIdx.x * 256 + threadIdx.x) * 8;
  const float* s = (i < NCv) ? (x0 + i) : (x1 + (i - NCv));
  float4_t a = *(const float4_t*)s;
  float4_t b = *(const float4_t*)(s + 4);
  short8 o;
  o[0] = (short)f2b(a[0]); o[1] = (short)f2b(a[1]);
  o[2] = (short)f2b(a[2]); o[3] = (short)f2b(a[3]);
  o[4] = (short)f2b(b[0]); o[5] = (short)f2b(b[1]);
  o[6] = (short)f2b(b[2]); o[7] = (short)f2b(b[3]);
  *(short8*)(xb + i) = o;
}

// all weight fp32->bf16 conversions/concats as one multi-job kernel
__global__ __launch_bounds__(256)
void prep_w(const float* fc1_w, const float* fc2_w,
            const float* in_w01, const float* out_w01,
            const float* in_w10, const float* out_w10,
            unsigned short* wfc1, unsigned short* wfc2,
            unsigned short* Wcat0, unsigned short* Wcat1,
            unsigned short* wout0, unsigned short* wout1)
{
  const float* src; unsigned short* dst; int n;
  switch (blockIdx.y) {
    case 0: src = fc1_w;             dst = wfc1;             n = 131072; break;
    case 1: src = fc2_w;             dst = wfc2;             n = 65536;  break;
    case 2: src = in_w01;            dst = Wcat0;            n = 196608; break;
    case 3: src = in_w10 + 512*256;  dst = Wcat0 + 768*256;  n = 65536;  break;
    case 4: src = in_w10;            dst = Wcat1;            n = 196608; break;
    case 5: src = in_w01 + 512*256;  dst = Wcat1 + 768*256;  n = 65536;  break;
    case 6: src = out_w01;           dst = wout0;            n = 65536;  break;
    default: src = out_w10;          dst = wout1;            n = 65536;  break;
  }
  int i = (blockIdx.x * 256 + threadIdx.x) * 4;
  if (i >= n) return;
  float4_t v = *(const float4_t*)(src + i);
  ushort4_t o;
  o[0] = f2b(v[0]); o[1] = f2b(v[1]); o[2] = f2b(v[2]); o[3] = f2b(v[3]);
  *(ushort4_t*)(dst + i) = o;
}

// bcat_h[1024]: [0:256)=bq ; [256:768)=bk/bv + noise@W ; [768:1024)=other bv
__global__ __launch_bounds__(256)
void prep_bcat(const float* in_w01, const float* in_b01,
               const float* in_w10, const float* in_b10,
               const float* kn, const float* vn,
               float* bcat0, float* bcat1)
{
  int j = blockIdx.x * 256 + threadIdx.x;   // 0..2047
  int h = j >> 10, c = j & 1023;
  const float* inw  = h ? in_w10 : in_w01;
  const float* inb  = h ? in_b10 : in_b01;
  const float* oinb = h ? in_b01 : in_b10;
  float v;
  if (c < 256) v = inb[c];
  else if (c < 768) {
    const float* nz = (c < 512 ? kn : vn) + h * 256;
    const float* wrow = inw + (size_t)c * 256;
    float s = 0.f;
    for (int k = 0; k < 256; ++k) s += nz[k] * wrow[k];
    v = inb[c] + s;
  } else v = oinb[512 + (c - 768)];
  (h ? bcat1 : bcat0)[c] = v;
}

// fused: rel = softmax(s row); k1in = xb * rel.  4 rows/block, wave per row.
__global__ __launch_bounds__(256)
void softmax_mul(const unsigned short* __restrict__ s,
                 const unsigned short* __restrict__ xb,
                 unsigned short* __restrict__ k1in)
{
  size_t row = (size_t)blockIdx.x * 4 + (threadIdx.x >> 6);
  int l = threadIdx.x & 63;
  const unsigned short* p = s + row * 256;
  float v[4];
#pragma unroll
  for (int j = 0; j < 4; ++j) v[j] = b2f(p[l + 64 * j]);
  float mx = fmaxf(fmaxf(v[0], v[1]), fmaxf(v[2], v[3]));
#pragma unroll
  for (int off = 32; off > 0; off >>= 1) mx = fmaxf(mx, __shfl_xor(mx, off, 64));
  float sum = 0.f;
#pragma unroll
  for (int j = 0; j < 4; ++j) { v[j] = expf(v[j] - mx); sum += v[j]; }
#pragma unroll
  for (int off = 32; off > 0; off >>= 1) sum += __shfl_xor(sum, off, 64);
  float inv = 1.f / sum;
  const unsigned short* xr = xb + row * 256;
  unsigned short* o = k1in + row * 256;
#pragma unroll
  for (int j = 0; j < 4; ++j)
    o[l + 64 * j] = f2b(v[j] * inv * b2f(xr[l + 64 * j]));
}

// per-(token,head) 2-slot attention over [2BN] tokens
__global__ __launch_bounds__(256)
void attn2(const unsigned short* __restrict__ qkv,   // [2BN,768] q|k0|v0
           const unsigned short* __restrict__ k1b,   // [2BN,256]
           const unsigned short* __restrict__ v1b,   // [2BN,256]
           unsigned short* __restrict__ ctx)         // [2BN,256]
{
  int tid = blockIdx.x * 256 + threadIdx.x;
  size_t tok = (size_t)(tid >> 3);
  int h = tid & 7;
  const unsigned short* q   = qkv + tok * 768 + h * 32;
  const unsigned short* k0p = q + 256;
  const unsigned short* v0p = q + 512;
  const unsigned short* k1p = k1b + tok * 256 + h * 32;
  const unsigned short* v1p = v1b + tok * 256 + h * 32;
  unsigned short* op = ctx + tok * 256 + h * 32;

  float s0 = 0.f, s1 = 0.f;
#pragma unroll
  for (int c = 0; c < 4; ++c) {
    short8 q8 = *(const short8*)(q + c * 8);
    short8 a8 = *(const short8*)(k0p + c * 8);
    short8 b8 = *(const short8*)(k1p + c * 8);
#pragma unroll
    for (int j = 0; j < 8; ++j) {
      float qf = b2f((unsigned short)q8[j]);
      s0 += qf * b2f((unsigned short)a8[j]);
      s1 += qf * b2f((unsigned short)b8[j]);
    }
  }
  const float sc = 0.17677669529663687f;  // 1/sqrt(32)
  s0 *= sc; s1 *= sc;
  float mx = fmaxf(s0, s1);
  float e0 = expf(s0 - mx), e1 = expf(s1 - mx);
  float inv = 1.f / (e0 + e1);
  e0 *= inv; e1 *= inv;
#pragma unroll
  for (int c = 0; c < 4; ++c) {
    short8 a8 = *(const short8*)(v0p + c * 8);
    short8 b8 = *(const short8*)(v1p + c * 8);
    short8 o8;
#pragma unroll
    for (int j = 0; j < 8; ++j)
      o8[j] = (short)f2b(e0 * b2f((unsigned short)a8[j]) + e1 * b2f((unsigned short)b8[j]));
    *(short8*)(op + c * 8) = o8;
  }
}

// ---------------------------------------------------------------------------
extern "C" void kernel_launch(void* const* d_in, const int* in_sizes, int n_in,
                              void* d_out, int out_size, void* d_ws, size_t ws_size,
                              hipStream_t stream)
{
  const float* x0     = (const float*)d_in[0];
  const float* x1     = (const float*)d_in[1];
  const float* fc1_w  = (const float*)d_in[2];
  const float* fc1_b  = (const float*)d_in[3];
  const float* fc2_w  = (const float*)d_in[4];
  const float* fc2_b  = (const float*)d_in[5];
  const float* in_w01 = (const float*)d_in[6];
  const float* in_b01 = (const float*)d_in[7];
  const float* out_w01= (const float*)d_in[8];
  const float* out_b01= (const float*)d_in[9];
  const float* in_w10 = (const float*)d_in[10];
  const float* in_b10 = (const float*)d_in[11];
  const float* out_w10= (const float*)d_in[12];
  const float* out_b10= (const float*)d_in[13];
  const float* kn     = (const float*)d_in[14];
  const float* vn     = (const float*)d_in[15];

  // -------- workspace layout (aliased by liveness) ----------------------
  char* ws = (char*)d_ws;
  unsigned short* xb   = (unsigned short*)ws; ws += TBNv * 256 * 2;   // 67MB  [cvt -> softmax_mul]; aliased later by ctx
  unsigned short* qkv  = (unsigned short*)ws; ws += (size_t)TBNv * 768 * 2; // 201MB [mega -> attn2]
  unsigned short* v1b  = (unsigned short*)ws; ws += TBNv * 256 * 2;   // 67MB  [mega -> attn2]
  unsigned short* hbuf = (unsigned short*)ws; ws += TBNv * 256 * 2;   // 67MB  [mega -> fc2]; aliased by k1in
  unsigned short* sbuf = (unsigned short*)ws; ws += TBNv * 256 * 2;   // 67MB  [fc2 -> softmax_mul]; aliased by k1b
  unsigned short* wfc1 = (unsigned short*)ws; ws += 131072 * 2;
  unsigned short* wfc2 = (unsigned short*)ws; ws += 65536 * 2;
  unsigned short* Wcat0= (unsigned short*)ws; ws += 262144 * 2;
  unsigned short* Wcat1= (unsigned short*)ws; ws += 262144 * 2;
  unsigned short* wout0= (unsigned short*)ws; ws += 65536 * 2;
  unsigned short* wout1= (unsigned short*)ws; ws += 65536 * 2;
  float* bcat0 = (float*)ws; ws += 1024 * 4;
  float* bcat1 = (float*)ws; ws += 1024 * 4;

  unsigned short* k1in = hbuf;   // alias: hbuf dead after fc2
  unsigned short* k1b  = sbuf;   // alias: sbuf dead after softmax_mul
  unsigned short* ctx  = xb;     // alias: xb dead after softmax_mul

  if (ws_size < (size_t)(ws - (char*)d_ws)) return;

  dim3 blk(256);

  // 1. input conversion (both tensors, one launch)
  cvt_x<<<16384, blk, 0, stream>>>(x0, x1, xb);
  // 2-3. weight prep
  prep_w<<<dim3(192, 8), blk, 0, stream>>>(fc1_w, fc2_w, in_w01, out_w01,
                                           in_w10, out_w10,
                                           wfc1, wfc2, Wcat0, Wcat1, wout0, wout1);
  prep_bcat<<<8, blk, 0, stream>>>(in_w01, in_b01, in_w10, in_b10, kn, vn,
                                   bcat0, bcat1);
  // 4. mega GEMM: qkv | V1 | fc1-GELU
  gemm_mega<<<10240, blk, 0, stream>>>(xb, Wcat0, Wcat1, wfc1,
                                       bcat0, bcat1, fc1_b, qkv, v1b, hbuf);
  // 5. fc2: s = h @ fc2_w.T + fc2_b
  gemm_b2<0><<<2048, blk, 0, stream>>>(hbuf, wfc2, wfc2, fc2_b, fc2_b,
                                       nullptr, nullptr, sbuf);
  // 6. rel = softmax(s); k1in = x * rel
  softmax_mul<<<32768, blk, 0, stream>>>(sbuf, xb, k1in);
  // 7. K1 = k1in @ Wk.T + bk   (raw in_b, no noise fold)
  gemm_b2<0><<<2048, blk, 0, stream>>>(k1in, Wcat0 + 256 * 256, Wcat1 + 256 * 256,
                                       in_b01 + 256, in_b10 + 256,
                                       nullptr, nullptr, k1b);
  // 8. 2-slot attention
  attn2<<<4096, blk, 0, stream>>>(qkv, k1b, v1b, ctx);
  // 9. out = ctx @ Wo.T + bo + x  (fp32, both directions)
  gemm_b2<2><<<2048, blk, 0, stream>>>(ctx, wout0, wout1, out_b01, out_b10,
                                       x0, x1, d_out);
}